// Round 15
// baseline (397.177 us; speedup 1.0000x reference)
//
#include <hip/hip_runtime.h>
#include <math.h>

#define TB    4096
#define TSEQ  320
#define NEEG  64
#define NTH   32
#define NH    16
#define NGEO  18
#define TILE_T 64
#define NTILES 5
#define XROWS2 70          // x rows per tile: t0-3 .. t0+66
#define H1ROWS 66          // h1 rows: t0-1 .. t0+64

typedef _Float16 f16x8 __attribute__((ext_vector_type(8)));
typedef _Float16 f16x2 __attribute__((ext_vector_type(2)));
typedef float f32x4 __attribute__((ext_vector_type(4)));
#define INV2048 4.8828125e-4f

// ws float offsets
#define OFF_W1F  0        // 10240 floats = 20480 halves: [kk][nb][hl][64][8]
#define OFF_W2F  10240    // 1536 floats = 3072 halves:   [kk2][hl][64][8]
#define OFF_B1   11776    // 32
#define OFF_B2   11808    // 16
#define OFF_GWT  11824    // 288  [i][h]
#define OFF_FC1T 12112    // 10240 [f][o]
#define OFF_FC2T 22352    // 256   [j][o]
#define OFF_ZP   22656    // 64 floats of zeros (DMA zero page)
#define OFF_DPF  32768    // DP: TB*160 floats

__global__ void __launch_bounds__(256)
prep_kernel(const float* __restrict__ c1w, const float* __restrict__ c1b,
            const float* __restrict__ s1,  const float* __restrict__ bb1,
            const float* __restrict__ mm1, const float* __restrict__ vv1,
            const float* __restrict__ c2w, const float* __restrict__ c2b,
            const float* __restrict__ s2,  const float* __restrict__ bb2,
            const float* __restrict__ mm2, const float* __restrict__ vv2,
            const float* __restrict__ gw,  const float* __restrict__ fc1w,
            const float* __restrict__ fc2w, float* __restrict__ ws)
{
    const int tid = threadIdx.x;
    _Float16* w1fp = reinterpret_cast<_Float16*>(ws + OFF_W1F);
    _Float16* w2fp = reinterpret_cast<_Float16*>(ws + OFF_W2F);

    // conv1 B-fragments: [kk][nb][hl][lane][j]; K = k*64 + i (i fast)
    for (int d = tid; d < 10240; d += 256) {
        int j = d & 7, l = (d >> 3) & 63, nbk = d >> 9;   // nbk = kk*2+nb
        int kk = nbk >> 1, nb = nbk & 1;
        int k = kk >> 1, i = (kk & 1) * 32 + ((l >> 4) * 8) + j;
        int c = nb * 16 + (l & 15);
        float inv = s1[c] / sqrtf(vv1[c] + 1e-5f);
        float wv = c1w[c * 320 + i * 5 + k] * inv;
        _Float16 hi = (_Float16)wv;
        _Float16 lo = (_Float16)((wv - (float)hi) * 2048.f);
        w1fp[((nbk * 2 + 0) * 64 + l) * 8 + j] = hi;
        w1fp[((nbk * 2 + 1) * 64 + l) * 8 + j] = lo;
    }
    // conv2 B-fragments: [kk2][hl][lane][j]; K = k*32 + c (c fast)
    for (int d = tid; d < 1536; d += 256) {
        int j = d & 7, l = (d >> 3) & 63, kk2 = d >> 9;
        int c = (l >> 4) * 8 + j;
        int o = l & 15;
        float inv = s2[o] / sqrtf(vv2[o] + 1e-5f);
        float wv = c2w[o * 96 + c * 3 + kk2] * inv;
        _Float16 hi = (_Float16)wv;
        _Float16 lo = (_Float16)((wv - (float)hi) * 2048.f);
        w2fp[((kk2 * 2 + 0) * 64 + l) * 8 + j] = hi;
        w2fp[((kk2 * 2 + 1) * 64 + l) * 8 + j] = lo;
    }
    if (tid < NTH) {
        float inv = s1[tid] / sqrtf(vv1[tid] + 1e-5f);
        ws[OFF_B1 + tid] = c1b[tid] * inv + bb1[tid] - mm1[tid] * inv;
    }
    if (tid < NH) {
        float inv = s2[tid] / sqrtf(vv2[tid] + 1e-5f);
        ws[OFF_B2 + tid] = c2b[tid] * inv + bb2[tid] - mm2[tid] * inv;
    }
    for (int d = tid; d < NGEO * NH; d += 256) {
        int i = d / NH, h = d - i * NH;
        ws[OFF_GWT + d] = gw[h * NGEO + i];
    }
    for (int d = tid; d < 160 * 64; d += 256) {
        int f = d / 64, o = d - f * 64;
        ws[OFF_FC1T + d] = fc1w[o * 160 + f];
    }
    if (tid < 256) {
        int j = tid / 4, o = tid - j * 4;
        ws[OFF_FC2T + tid] = fc2w[o * 64 + j];
    }
    if (tid < 64) ws[OFF_ZP + tid] = 0.f;   // DMA zero page
}

// ---------- Kernel A: fused conv1+conv2+geo+ALIF-scan, one block per batch element ----------
// E/C never touch HBM: conv2 -> E_lds, geo -> C_lds, scan (lanes 0-15) -> DP.
__global__ void __launch_bounds__(256, 2)
convm_kernel(const float* __restrict__ xeeg, const float* __restrict__ xgeo,
             const float* __restrict__ ws,   const float* __restrict__ geo_b,
             const float* __restrict__ gamma, float* __restrict__ DP)
{
    __shared__ __align__(16) float xbuf[2][XROWS2 * 64];     // 35840 B (DMA dest; converted in-place to f16 hi/lo planes)
    __shared__ __align__(16) float xg32[18 * 64];            // 4608 B  (DMA dest, single)
    __shared__ __align__(16) _Float16 w2f[3][2][64][8];      // 6144 B  (conv2 B-frags)
    __shared__ __align__(16) _Float16 h1h[H1ROWS * 32];      // 4224 B
    __shared__ __align__(16) _Float16 h1l[H1ROWS * 32];      // 4224 B
    __shared__ __align__(16) float E_lds[TILE_T][20];        // 5120 B  (pad 20: 2-way-free banks)
    __shared__ __align__(16) float C_lds[2][TILE_T][20];     // 10240 B
    __shared__ __align__(16) float gws[NGEO * NH];           // 1152 B
    __shared__ float b1s[32], b2s[16], gbs[16], gams[16];
    // total ~70.2 KB -> 2 blocks/CU

    const int b = blockIdx.x, tid = threadIdx.x;
    const int l = tid & 63, w = tid >> 6;
    const int lrow = l & 15, lkg = l >> 4;
    const int nb = w >> 1, wsub = w & 1;
    const int ug = tid >> 2, hq = tid & 3;     // geo mapping: row ug, h-group hq

    const float* xb  = xeeg + (size_t)b * TSEQ * NEEG;
    const float* xgb = xgeo + (size_t)b * TSEQ * NGEO;
    const float* zp  = ws + OFF_ZP;

    // DMA one tile's x (70 rows of 64 fp32) + x_geo (18 chunks of 64 fp32)
#define STAGE_DMA(buf, t0n) do {                                                     \
        for (int c_ = w; c_ < XROWS2; c_ += 4) {                                     \
            int tg_ = (t0n) - 3 + c_;                                                \
            const float* s_ = (tg_ >= 0 && tg_ < TSEQ)                               \
                              ? (xb + (size_t)tg_ * 64 + l) : zp;                    \
            __builtin_amdgcn_global_load_lds(                                        \
                (const __attribute__((address_space(1))) void*)s_,                   \
                (__attribute__((address_space(3))) void*)&xbuf[(buf)][c_ * 64],      \
                4, 0, 0);                                                            \
        }                                                                            \
        for (int c_ = w; c_ < 18; c_ += 4) {                                         \
            const float* s_ = xgb + (size_t)(t0n) * NGEO + c_ * 64 + l;              \
            __builtin_amdgcn_global_load_lds(                                        \
                (const __attribute__((address_space(1))) void*)s_,                   \
                (__attribute__((address_space(3))) void*)&xg32[c_ * 64],             \
                4, 0, 0);                                                            \
        }                                                                            \
    } while (0)

    // ---- conv1 B-fragments -> registers (per-wave nb half) ----
    f16x8 B1h[10], B1l[10];
    {
        const f16x8* wsrc = reinterpret_cast<const f16x8*>(ws + OFF_W1F);
        #pragma unroll
        for (int kk = 0; kk < 10; ++kk) {
            B1h[kk] = wsrc[((kk * 2 + nb) * 2 + 0) * 64 + l];
            B1l[kk] = wsrc[((kk * 2 + nb) * 2 + 1) * 64 + l];
        }
    }
    // ---- w2 + constants into LDS ----
    {
        const float4* s2 = reinterpret_cast<const float4*>(ws + OFF_W2F);
        float4* d2 = reinterpret_cast<float4*>(&w2f[0][0][0][0]);
        for (int p = tid; p < 384; p += 256) d2[p] = s2[p];
        if (tid < 32) b1s[tid] = ws[OFF_B1 + tid];
        if (tid < 16) {
            b2s[tid] = ws[OFF_B2 + tid];
            gbs[tid] = geo_b[tid];
            gams[tid] = gamma[tid];
        }
        for (int p = tid; p < NGEO * NH; p += 256) gws[p] = ws[OFF_GWT + p];
    }
    // ---- ALIF scan state (lanes 0-15 meaningful) ----
    float eta = 0.f, memv = 0.f, li = 0.f, ps = 0.f, accF = 0.f, accS = 0.f;

    // ---- prologue: DMA tile 0; barrier drains it (and makes w2f/consts visible) ----
    STAGE_DMA(0, 0);
    __syncthreads();

    for (int jt = 0; jt < NTILES; ++jt) {
        const int t0 = jt * TILE_T;
        const int cur = jt & 1;
        _Float16* xh = reinterpret_cast<_Float16*>(&xbuf[cur][0]);
        _Float16* xl = xh + XROWS2 * 64;

        // ---- S-read: float2's from xbuf[cur] into regs; geo -> C_lds[cur] ----
        float2 xr2[9];
        #pragma unroll
        for (int q = 0; q < 9; ++q) {
            int p = tid + q * 256;
            if (p < XROWS2 * 32) {
                int xr = p >> 5, ip = (p & 31) * 2;
                xr2[q] = *reinterpret_cast<const float2*>(&xbuf[cur][xr * 64 + ip]);
            }
        }
        {
            float z0 = gbs[hq * 4 + 0], z1 = gbs[hq * 4 + 1];
            float z2 = gbs[hq * 4 + 2], z3 = gbs[hq * 4 + 3];
            const float* xgr = &xg32[ug * NGEO];
            #pragma unroll
            for (int ii = 0; ii < NGEO; ++ii) {
                float xv = xgr[ii];
                float4 wv = *reinterpret_cast<const float4*>(&gws[ii * 16 + hq * 4]);
                z0 = fmaf(xv, wv.x, z0);
                z1 = fmaf(xv, wv.y, z1);
                z2 = fmaf(xv, wv.z, z2);
                z3 = fmaf(xv, wv.w, z3);
            }
            float4 cv;
            cv.x = gams[hq * 4 + 0] * (1.f / (1.f + expf(-z0)));
            cv.y = gams[hq * 4 + 1] * (1.f / (1.f + expf(-z1)));
            cv.z = gams[hq * 4 + 2] * (1.f / (1.f + expf(-z2)));
            cv.w = gams[hq * 4 + 3] * (1.f / (1.f + expf(-z3)));
            *reinterpret_cast<float4*>(&C_lds[cur][ug][hq * 4]) = cv;
        }
        __syncthreads();   // barrier S1: all reads of xbuf[cur] done; C_lds[cur] staged

        // ---- S-write: cvt regs -> f16 hi/lo planes, in place (XOR-swizzled) ----
        #pragma unroll
        for (int q = 0; q < 9; ++q) {
            int p = tid + q * 256;
            if (p < XROWS2 * 32) {
                int xr = p >> 5, ip = (p & 31) * 2;
                float f0 = xr2[q].x, f1 = xr2[q].y;
                _Float16 h0 = (_Float16)f0, h1v = (_Float16)f1;
                f16x2 vh = {h0, h1v};
                f16x2 vl = {(_Float16)((f0 - (float)h0) * 2048.f),
                            (_Float16)((f1 - (float)h1v) * 2048.f)};
                int idx = xr * 64 + (((ip >> 3) ^ (xr & 7)) << 3) + (ip & 7);
                *reinterpret_cast<f16x2*>(&xh[idx]) = vh;
                *reinterpret_cast<f16x2*>(&xl[idx]) = vl;
            }
        }
        __syncthreads();   // barrier A: planes staged

        // ---- C1: issue DMA for tile jt+1, then conv1 MFMAs ----
        if (jt + 1 < NTILES) STAGE_DMA(cur ^ 1, (jt + 1) * TILE_T);
        __builtin_amdgcn_s_setprio(1);
        {
            const float bia = b1s[nb * 16 + lrow];
            #pragma unroll
            for (int pi = 0; pi < 3; ++pi) {
                if (pi == 2 && ((jt & 1) != wsub)) break;
                const int mb = (pi < 2) ? (wsub + pi * 2) : 4;
                const int mbase = mb * 16;
                int s = mbase + lrow; if (s > H1ROWS - 1) s = H1ROWS - 1;
                f32x4 aH = {0.f, 0.f, 0.f, 0.f};
                f32x4 aM = aH, aL = aH;
                #pragma unroll
                for (int kk = 0; kk < 10; ++kk) {
                    const int xr = s + (kk >> 1);
                    const int gx = (kk & 1) * 4 + lkg;
                    const int off = xr * 64 + ((gx ^ (xr & 7)) << 3);
                    f16x8 Ah = *reinterpret_cast<const f16x8*>(&xh[off]);
                    f16x8 Al = *reinterpret_cast<const f16x8*>(&xl[off]);
                    aH = __builtin_amdgcn_mfma_f32_16x16x32_f16(Ah, B1h[kk], aH, 0, 0, 0);
                    aM = __builtin_amdgcn_mfma_f32_16x16x32_f16(Ah, B1l[kk], aM, 0, 0, 0);
                    aL = __builtin_amdgcn_mfma_f32_16x16x32_f16(Al, B1h[kk], aL, 0, 0, 0);
                }
                #pragma unroll
                for (int r = 0; r < 4; ++r) {
                    int so = mbase + lkg * 4 + r;
                    if (so < H1ROWS) {
                        int tg = t0 - 1 + so;
                        bool v = (tg >= 0 && tg < TSEQ);
                        float val = v ? fmaxf(fmaf(aM[r] + aL[r], INV2048, aH[r]) + bia, 0.f) : 0.f;
                        int key = (so >> 1) & 3;
                        int g = (nb * 2 + (lrow >> 3)) ^ key;
                        int idx = so * 32 + (g << 3) + (lrow & 7);
                        _Float16 hh = (_Float16)val;
                        h1h[idx] = hh;
                        h1l[idx] = (_Float16)((val - (float)hh) * 2048.f);
                    }
                }
            }
        }
        __builtin_amdgcn_s_setprio(0);
        __syncthreads();   // barrier B: h1 complete; drains jt+1 DMAs

        // ---- C2: conv2 (B-frags from LDS) -> E_lds ----
        {
            const int ub = w * 16;
            f32x4 aH = {0.f, 0.f, 0.f, 0.f};
            f32x4 aM = aH, aL = aH;
            __builtin_amdgcn_s_setprio(1);
            #pragma unroll
            for (int kk = 0; kk < 3; ++kk) {
                int srow = ub + lrow + kk;
                int off = srow * 32 + ((lkg ^ ((srow >> 1) & 3)) << 3);
                f16x8 Ah = *reinterpret_cast<const f16x8*>(&h1h[off]);
                f16x8 Al = *reinterpret_cast<const f16x8*>(&h1l[off]);
                f16x8 Bh = *reinterpret_cast<const f16x8*>(&w2f[kk][0][l][0]);
                f16x8 Bl = *reinterpret_cast<const f16x8*>(&w2f[kk][1][l][0]);
                aH = __builtin_amdgcn_mfma_f32_16x16x32_f16(Ah, Bh, aH, 0, 0, 0);
                aM = __builtin_amdgcn_mfma_f32_16x16x32_f16(Ah, Bl, aM, 0, 0, 0);
                aL = __builtin_amdgcn_mfma_f32_16x16x32_f16(Al, Bh, aL, 0, 0, 0);
            }
            __builtin_amdgcn_s_setprio(0);
            const float bia = b2s[lrow];
            #pragma unroll
            for (int r = 0; r < 4; ++r)
                E_lds[ub + lkg * 4 + r][lrow] =
                    fmaxf(fmaf(aM[r] + aL[r], INV2048, aH[r]) + bia, 0.f);
        }
        __syncthreads();   // barrier C: E_lds complete

        // ---- scan: lanes 0-15 (h = tid), sequential over this tile ----
        if (tid < 16) {
            const int h = tid;
            for (int tt = 0; tt < TILE_T; ++tt) {
                float e = E_lds[tt][h];
                float c = C_lds[cur][tt][h];
                eta = 0.36f * eta + 0.64f * ps;
                float theta = 0.5f + 1.8f * eta - c;
                memv = 0.8f * memv + e;
                float spk = (memv - theta >= 0.f) ? 1.f : 0.f;
                memv *= (1.f - spk);
                li = 0.9f * li + spk;
                ps = spk;
                int t = t0 + tt;
                if (((t >> 4) & 1) == 0) accF += li; else accS += li;
                if ((t & 31) == 31) {
                    DP[(size_t)b * 160 + h * 10 + (t >> 5)] = (accS - accF) * 0.0625f;
                    accF = 0.f; accS = 0.f;
                }
            }
        }
        // no trailing barrier: next S-read reads xbuf[cur^1]/xg32 (DMA-complete at
        // barrier B); geo(jt+1) writes C_lds[cur^1] (disjoint from scan's C_lds[cur]);
        // E_lds next written by conv2(jt+1) after B(jt+1) -- scan wave passes S1(jt+1)
        // only after finishing the scan, so ordering holds.
    }
#undef STAGE_DMA
}

// ---------- Kernel C: fc1+fc2, 4 batch per block ----------
__global__ void __launch_bounds__(256)
fc_kernel(const float* __restrict__ DP, const float* __restrict__ ws,
          const float* __restrict__ fc1_b, const float* __restrict__ fc2_b,
          float* __restrict__ out)
{
    __shared__ float sh_dp[4][160];
    __shared__ float mid[4][64];
    const int tid = threadIdx.x;
    const int b0 = blockIdx.x * 4;
    for (int p = tid; p < 640; p += 256)
        sh_dp[p / 160][p - (p / 160) * 160] = DP[(size_t)b0 * 160 + p];
    __syncthreads();
    {
        const int bl = tid >> 6, o = tid & 63;
        const float* __restrict__ fc1t = ws + OFF_FC1T;
        float z = fc1_b[o];
        for (int f = 0; f < 160; ++f) z = fmaf(sh_dp[bl][f], fc1t[f * 64 + o], z);
        mid[bl][o] = fmaxf(z, 0.f);
    }
    __syncthreads();
    if (tid < 16) {
        const int bl = tid >> 2, oo = tid & 3;
        const float* __restrict__ fc2t = ws + OFF_FC2T;
        float z = fc2_b[oo];
        #pragma unroll
        for (int jj = 0; jj < 64; ++jj) z = fmaf(mid[bl][jj], fc2t[jj * 4 + oo], z);
        out[(size_t)(b0 + bl) * 4 + oo] = z;
    }
}

extern "C" void kernel_launch(void* const* d_in, const int* in_sizes, int n_in,
                              void* d_out, int out_size, void* d_ws, size_t ws_size,
                              hipStream_t stream)
{
    const float* xeeg = (const float*)d_in[0];
    const float* xgeo = (const float*)d_in[1];
    const float* c1w  = (const float*)d_in[2];
    const float* c1b  = (const float*)d_in[3];
    const float* s1   = (const float*)d_in[4];
    const float* bb1  = (const float*)d_in[5];
    const float* mm1  = (const float*)d_in[6];
    const float* vv1  = (const float*)d_in[7];
    const float* c2w  = (const float*)d_in[8];
    const float* c2b  = (const float*)d_in[9];
    const float* s2   = (const float*)d_in[10];
    const float* bb2  = (const float*)d_in[11];
    const float* mm2  = (const float*)d_in[12];
    const float* vv2  = (const float*)d_in[13];
    const float* gw   = (const float*)d_in[14];
    const float* gb   = (const float*)d_in[15];
    const float* gam  = (const float*)d_in[16];
    const float* fc1w = (const float*)d_in[17];
    const float* fc1b = (const float*)d_in[18];
    const float* fc2w = (const float*)d_in[19];
    const float* fc2b = (const float*)d_in[20];
    float* ws   = (float*)d_ws;
    float* outp = (float*)d_out;

    hipLaunchKernelGGL(prep_kernel, dim3(1), dim3(256), 0, stream,
                       c1w, c1b, s1, bb1, mm1, vv1, c2w, c2b, s2, bb2, mm2, vv2,
                       gw, fc1w, fc2w, ws);

    float* DP = ws + OFF_DPF;
    hipLaunchKernelGGL(convm_kernel, dim3(TB), dim3(256), 0, stream,
                       xeeg, xgeo, ws, gb, gam, DP);
    hipLaunchKernelGGL(fc_kernel, dim3(TB / 4), dim3(256), 0, stream,
                       DP, ws, fc1b, fc2b, outp);
}

// Round 16
// 310.548 us; speedup vs baseline: 1.2790x; 1.2790x over previous
//
#include <hip/hip_runtime.h>
#include <math.h>

#define TB    4096
#define TSEQ  320
#define NEEG  64
#define NTH   32
#define NH    16
#define NGEO  18
#define TILE_T 64
#define NTILES 5
#define XROWS2 70
#define H1ROWS 66

typedef _Float16 f16x8 __attribute__((ext_vector_type(8)));
typedef _Float16 f16x2 __attribute__((ext_vector_type(2)));
typedef float f32x4 __attribute__((ext_vector_type(4)));
#define INV2048 4.8828125e-4f

// ws float offsets
#define OFF_W1F  0        // 10240 floats = 20480 halves: [kk][nb][hl][64][8]
#define OFF_W2F  10240    // 1536 floats = 3072 halves:   [kk2][hl][64][8]
#define OFF_B1   11776    // 32
#define OFF_B2   11808    // 16
#define OFF_GWT  11824    // 288  [i][h]
#define OFF_FC1T 12112    // 10240 [f][o]
#define OFF_FC2T 22352    // 256   [j][o]
#define OFF_ZP   22656    // 64 floats of zeros (DMA zero page)
#define OFF_E    32768
#define SZ_EC    (TB*TSEQ*NH)            // 20971520
#define OFF_C    (OFF_E + SZ_EC)
#define OFF_DP   (OFF_C + SZ_EC)
#define SZ_DP    (TB*160)
#define REQ_FLOATS ((size_t)OFF_DP + SZ_DP)
#define REQ_BYTES  (REQ_FLOATS * 4)      // 170,524,672

__global__ void __launch_bounds__(256)
prep_kernel(const float* __restrict__ c1w, const float* __restrict__ c1b,
            const float* __restrict__ s1,  const float* __restrict__ bb1,
            const float* __restrict__ mm1, const float* __restrict__ vv1,
            const float* __restrict__ c2w, const float* __restrict__ c2b,
            const float* __restrict__ s2,  const float* __restrict__ bb2,
            const float* __restrict__ mm2, const float* __restrict__ vv2,
            const float* __restrict__ gw,  const float* __restrict__ fc1w,
            const float* __restrict__ fc2w, float* __restrict__ ws)
{
    const int tid = threadIdx.x;
    _Float16* w1fp = reinterpret_cast<_Float16*>(ws + OFF_W1F);
    _Float16* w2fp = reinterpret_cast<_Float16*>(ws + OFF_W2F);

    // conv1 B-fragments: [kk][nb][hl][lane][j]; K = k*64 + i (i fast)
    for (int d = tid; d < 10240; d += 256) {
        int j = d & 7, l = (d >> 3) & 63, nbk = d >> 9;   // nbk = kk*2+nb
        int kk = nbk >> 1, nb = nbk & 1;
        int k = kk >> 1, i = (kk & 1) * 32 + ((l >> 4) * 8) + j;
        int c = nb * 16 + (l & 15);
        float inv = s1[c] / sqrtf(vv1[c] + 1e-5f);
        float wv = c1w[c * 320 + i * 5 + k] * inv;
        _Float16 hi = (_Float16)wv;
        _Float16 lo = (_Float16)((wv - (float)hi) * 2048.f);
        w1fp[((nbk * 2 + 0) * 64 + l) * 8 + j] = hi;
        w1fp[((nbk * 2 + 1) * 64 + l) * 8 + j] = lo;
    }
    // conv2 B-fragments: [kk2][hl][lane][j]; K = k*32 + c (c fast)
    for (int d = tid; d < 1536; d += 256) {
        int j = d & 7, l = (d >> 3) & 63, kk2 = d >> 9;
        int c = (l >> 4) * 8 + j;
        int o = l & 15;
        float inv = s2[o] / sqrtf(vv2[o] + 1e-5f);
        float wv = c2w[o * 96 + c * 3 + kk2] * inv;
        _Float16 hi = (_Float16)wv;
        _Float16 lo = (_Float16)((wv - (float)hi) * 2048.f);
        w2fp[((kk2 * 2 + 0) * 64 + l) * 8 + j] = hi;
        w2fp[((kk2 * 2 + 1) * 64 + l) * 8 + j] = lo;
    }
    if (tid < NTH) {
        float inv = s1[tid] / sqrtf(vv1[tid] + 1e-5f);
        ws[OFF_B1 + tid] = c1b[tid] * inv + bb1[tid] - mm1[tid] * inv;
    }
    if (tid < NH) {
        float inv = s2[tid] / sqrtf(vv2[tid] + 1e-5f);
        ws[OFF_B2 + tid] = c2b[tid] * inv + bb2[tid] - mm2[tid] * inv;
    }
    for (int d = tid; d < NGEO * NH; d += 256) {
        int i = d / NH, h = d - i * NH;
        ws[OFF_GWT + d] = gw[h * NGEO + i];
    }
    for (int d = tid; d < 160 * 64; d += 256) {
        int f = d / 64, o = d - f * 64;
        ws[OFF_FC1T + d] = fc1w[o * 160 + f];
    }
    if (tid < 256) {
        int j = tid / 4, o = tid - j * 4;
        ws[OFF_FC2T + tid] = fc2w[o * 64 + j];
    }
    if (tid < 64) ws[OFF_ZP + tid] = 0.f;   // DMA zero page
}

// ---------- Kernel A: MFMA conv1+conv2+geo; DMA double-buffer; in-place f16 planes ----------
// __launch_bounds__(256,2): yields VGPR=128 with no spill (r12); (256,3+) provably
// makes the compiler shrink to 84 VGPR and spill the B-fragment set (r11: FETCH 3.7x).
// E/C stored in [t4][b][h][4] so scan_kernel reads are block-contiguous (r13 layout).
__global__ void __launch_bounds__(256, 2)
convm_kernel(const float* __restrict__ xeeg, const float* __restrict__ xgeo,
             const float* __restrict__ ws,   const float* __restrict__ geo_b,
             const float* __restrict__ gamma,
             float* __restrict__ E, float* __restrict__ C)
{
    __shared__ __align__(16) float xbuf[2][XROWS2 * 64];     // 35840 B (DMA dest; cur buf converted in-place to f16 hi/lo planes)
    __shared__ __align__(16) float xg32[18 * 64];            // 4608 B  (DMA dest, single)
    __shared__ __align__(16) _Float16 h1h[H1ROWS * 32];      // 4224 B
    __shared__ __align__(16) _Float16 h1l[H1ROWS * 32];      // 4224 B
    __shared__ __align__(16) float gws[NGEO * NH];           // 1152 B
    __shared__ float b1s[32], b2s[16], gbs[16], gams[16];
    // total ~49.2 KB

    const int b = blockIdx.x, tid = threadIdx.x;
    const int l = tid & 63, w = tid >> 6;
    const int lrow = l & 15, lkg = l >> 4;
    const int nb = w >> 1, wsub = w & 1;
    const int ug = tid >> 2, hq = tid & 3;     // geo mapping: row ug, h-group hq

    const float* xb  = xeeg + (size_t)b * TSEQ * NEEG;
    const float* xgb = xgeo + (size_t)b * TSEQ * NGEO;
    const float* zp  = ws + OFF_ZP;

    // DMA one tile's x (70 rows of 64 fp32) + x_geo (18 chunks of 64 fp32)
#define STAGE_DMA(buf, t0n) do {                                                     \
        for (int c_ = w; c_ < XROWS2; c_ += 4) {                                     \
            int tg_ = (t0n) - 3 + c_;                                                \
            const float* s_ = (tg_ >= 0 && tg_ < TSEQ)                               \
                              ? (xb + (size_t)tg_ * 64 + l) : zp;                    \
            __builtin_amdgcn_global_load_lds(                                        \
                (const __attribute__((address_space(1))) void*)s_,                   \
                (__attribute__((address_space(3))) void*)&xbuf[(buf)][c_ * 64],      \
                4, 0, 0);                                                            \
        }                                                                            \
        for (int c_ = w; c_ < 18; c_ += 4) {                                         \
            const float* s_ = xgb + (size_t)(t0n) * NGEO + c_ * 64 + l;              \
            __builtin_amdgcn_global_load_lds(                                        \
                (const __attribute__((address_space(1))) void*)s_,                   \
                (__attribute__((address_space(3))) void*)&xg32[c_ * 64],             \
                4, 0, 0);                                                            \
        }                                                                            \
    } while (0)

    // ---- conv1 + conv2 B-fragments -> registers ----
    f16x8 B1h[10], B1l[10], B2h[3], B2l[3];
    {
        const f16x8* wsrc = reinterpret_cast<const f16x8*>(ws + OFF_W1F);
        #pragma unroll
        for (int kk = 0; kk < 10; ++kk) {
            B1h[kk] = wsrc[((kk * 2 + nb) * 2 + 0) * 64 + l];
            B1l[kk] = wsrc[((kk * 2 + nb) * 2 + 1) * 64 + l];
        }
        const f16x8* wsrc2 = reinterpret_cast<const f16x8*>(ws + OFF_W2F);
        #pragma unroll
        for (int kk = 0; kk < 3; ++kk) {
            B2h[kk] = wsrc2[(kk * 2 + 0) * 64 + l];
            B2l[kk] = wsrc2[(kk * 2 + 1) * 64 + l];
        }
    }
    // ---- constants into LDS ----
    {
        if (tid < 32) b1s[tid] = ws[OFF_B1 + tid];
        if (tid < 16) {
            b2s[tid] = ws[OFF_B2 + tid];
            gbs[tid] = geo_b[tid];
            gams[tid] = gamma[tid];
        }
        for (int p = tid; p < NGEO * NH; p += 256) gws[p] = ws[OFF_GWT + p];
    }
    // ---- prologue: DMA tile 0; barrier drains it ----
    STAGE_DMA(0, 0);
    __syncthreads();

    for (int jt = 0; jt < NTILES; ++jt) {
        const int t0 = jt * TILE_T;
        const int cur = jt & 1;
        _Float16* xh = reinterpret_cast<_Float16*>(&xbuf[cur][0]);
        _Float16* xl = xh + XROWS2 * 64;

        // ---- S-read: 9 float2 from xbuf[cur] into regs; geo -> C [t4][b][h][4] ----
        float2 xr2[9];
        #pragma unroll
        for (int q = 0; q < 9; ++q) {
            int p = tid + q * 256;
            if (p < 2240) {
                int xr = p >> 5, ip = (p & 31) * 2;
                xr2[q] = *reinterpret_cast<const float2*>(&xbuf[cur][xr * 64 + ip]);
            }
        }
        {
            float z0 = gbs[hq * 4 + 0], z1 = gbs[hq * 4 + 1];
            float z2 = gbs[hq * 4 + 2], z3 = gbs[hq * 4 + 3];
            const float* xgr = &xg32[ug * NGEO];
            #pragma unroll
            for (int ii = 0; ii < NGEO; ++ii) {
                float xv = xgr[ii];
                float4 wv = *reinterpret_cast<const float4*>(&gws[ii * 16 + hq * 4]);
                z0 = fmaf(xv, wv.x, z0);
                z1 = fmaf(xv, wv.y, z1);
                z2 = fmaf(xv, wv.z, z2);
                z3 = fmaf(xv, wv.w, z3);
            }
            const int t4o = (t0 + ug) >> 2, tt = ug & 3;
            float* cp = C + (((size_t)t4o * TB + b) * 16 + hq * 4) * 4 + tt;
            cp[0]  = gams[hq * 4 + 0] * (1.f / (1.f + expf(-z0)));
            cp[4]  = gams[hq * 4 + 1] * (1.f / (1.f + expf(-z1)));
            cp[8]  = gams[hq * 4 + 2] * (1.f / (1.f + expf(-z2)));
            cp[12] = gams[hq * 4 + 3] * (1.f / (1.f + expf(-z3)));
        }
        __syncthreads();   // barrier S1: all reads of xbuf[cur] done

        // ---- S-write: cvt regs -> f16 hi/lo planes, in place (XOR-swizzled) ----
        #pragma unroll
        for (int q = 0; q < 9; ++q) {
            int p = tid + q * 256;
            if (p < 2240) {
                int xr = p >> 5, ip = (p & 31) * 2;
                float f0 = xr2[q].x, f1 = xr2[q].y;
                _Float16 h0 = (_Float16)f0, h1v = (_Float16)f1;
                f16x2 vh = {h0, h1v};
                f16x2 vl = {(_Float16)((f0 - (float)h0) * 2048.f),
                            (_Float16)((f1 - (float)h1v) * 2048.f)};
                int idx = xr * 64 + (((ip >> 3) ^ (xr & 7)) << 3) + (ip & 7);
                *reinterpret_cast<f16x2*>(&xh[idx]) = vh;
                *reinterpret_cast<f16x2*>(&xl[idx]) = vl;
            }
        }
        __syncthreads();   // barrier A: planes staged

        // ---- C1: issue DMA for tile jt+1, then conv1 MFMAs ----
        if (jt + 1 < NTILES) STAGE_DMA(cur ^ 1, (jt + 1) * TILE_T);
        __builtin_amdgcn_s_setprio(1);
        {
            const float bia = b1s[nb * 16 + lrow];
            #pragma unroll
            for (int pi = 0; pi < 3; ++pi) {
                if (pi == 2 && ((jt & 1) != wsub)) break;
                const int mb = (pi < 2) ? (wsub + pi * 2) : 4;
                const int mbase = mb * 16;
                int s = mbase + lrow; if (s > 65) s = 65;
                f32x4 aH = {0.f, 0.f, 0.f, 0.f};
                f32x4 aM = aH, aL = aH;
                #pragma unroll
                for (int kk = 0; kk < 10; ++kk) {
                    const int xr = s + (kk >> 1);
                    const int gx = (kk & 1) * 4 + lkg;
                    const int off = xr * 64 + ((gx ^ (xr & 7)) << 3);
                    f16x8 Ah = *reinterpret_cast<const f16x8*>(&xh[off]);
                    f16x8 Al = *reinterpret_cast<const f16x8*>(&xl[off]);
                    aH = __builtin_amdgcn_mfma_f32_16x16x32_f16(Ah, B1h[kk], aH, 0, 0, 0);
                    aM = __builtin_amdgcn_mfma_f32_16x16x32_f16(Ah, B1l[kk], aM, 0, 0, 0);
                    aL = __builtin_amdgcn_mfma_f32_16x16x32_f16(Al, B1h[kk], aL, 0, 0, 0);
                }
                #pragma unroll
                for (int r = 0; r < 4; ++r) {
                    int so = mbase + lkg * 4 + r;
                    if (so < 66) {
                        int tg = t0 - 1 + so;
                        bool v = (tg >= 0 && tg < TSEQ);
                        float val = v ? fmaxf(fmaf(aM[r] + aL[r], INV2048, aH[r]) + bia, 0.f) : 0.f;
                        int key = (so >> 1) & 3;
                        int g = (nb * 2 + (lrow >> 3)) ^ key;
                        int idx = so * 32 + (g << 3) + (lrow & 7);
                        _Float16 hh = (_Float16)val;
                        h1h[idx] = hh;
                        h1l[idx] = (_Float16)((val - (float)hh) * 2048.f);
                    }
                }
            }
        }
        __builtin_amdgcn_s_setprio(0);
        __syncthreads();   // barrier B: h1 complete; drains jt+1 DMAs

        // ---- C2: conv2 (B-frags in regs) -> E [t4][b][h][4] ----
        {
            const int ub = w * 16;
            f32x4 aH = {0.f, 0.f, 0.f, 0.f};
            f32x4 aM = aH, aL = aH;
            __builtin_amdgcn_s_setprio(1);
            #pragma unroll
            for (int kk = 0; kk < 3; ++kk) {
                int srow = ub + lrow + kk;
                int off = srow * 32 + ((lkg ^ ((srow >> 1) & 3)) << 3);
                f16x8 Ah = *reinterpret_cast<const f16x8*>(&h1h[off]);
                f16x8 Al = *reinterpret_cast<const f16x8*>(&h1l[off]);
                aH = __builtin_amdgcn_mfma_f32_16x16x32_f16(Ah, B2h[kk], aH, 0, 0, 0);
                aM = __builtin_amdgcn_mfma_f32_16x16x32_f16(Ah, B2l[kk], aM, 0, 0, 0);
                aL = __builtin_amdgcn_mfma_f32_16x16x32_f16(Al, B2h[kk], aL, 0, 0, 0);
            }
            __builtin_amdgcn_s_setprio(0);
            const float bia = b2s[lrow];
            float4 ev;
            float* evp = reinterpret_cast<float*>(&ev);
            #pragma unroll
            for (int r = 0; r < 4; ++r)
                evp[r] = fmaxf(fmaf(aM[r] + aL[r], INV2048, aH[r]) + bia, 0.f);
            const int t4o = ((t0 + ub) >> 2) + lkg;
            float* ep = E + (((size_t)t4o * TB + b) * 16 + lrow) * 4;
            *reinterpret_cast<float4*>(ep) = ev;
        }
        // no trailing barrier: C2 reads h1 only; next S-read reads xbuf[cur^1]
        // and xg32 (both DMA-complete at barrier B); first write to those regions
        // happens after the next barriers.
    }
#undef STAGE_DMA
}

// ---------- Kernel B: ALIF scan; E/C in [t4][b][h][4] -> fully coalesced reads ----------
__global__ void __launch_bounds__(256)
scan_kernel(const float* __restrict__ E, const float* __restrict__ C,
            float* __restrict__ DP)
{
    const int tid = threadIdx.x;
    const int h = tid & 15;
    const int b = blockIdx.x * 16 + (tid >> 4);
    const float4* e4 = reinterpret_cast<const float4*>(E);
    const float4* c4 = reinterpret_cast<const float4*>(C);
    const size_t idx = (size_t)b * 16 + h;          // within a t4 slab
    const size_t slab = (size_t)TB * 16;            // float4s per t4

    float eta = 0.f, memv = 0.f, li = 0.f, ps = 0.f, accF = 0.f, accS = 0.f;
    float4 ev = e4[idx], cv = c4[idx];
    for (int t4 = 0; t4 < 80; ++t4) {
        float4 en, cn;
        if (t4 < 79) { en = e4[(size_t)(t4 + 1) * slab + idx]; cn = c4[(size_t)(t4 + 1) * slab + idx]; }
        const float* evp = reinterpret_cast<const float*>(&ev);
        const float* cvp = reinterpret_cast<const float*>(&cv);
        #pragma unroll
        for (int tt = 0; tt < 4; ++tt) {
            float e = evp[tt], c = cvp[tt];
            eta = 0.36f * eta + 0.64f * ps;
            float theta = 0.5f + 1.8f * eta - c;
            memv = 0.8f * memv + e;
            float spk = (memv - theta >= 0.f) ? 1.f : 0.f;
            memv *= (1.f - spk);
            li = 0.9f * li + spk;
            ps = spk;
            int t = t4 * 4 + tt;
            if (((t >> 4) & 1) == 0) accF += li; else accS += li;
        }
        if ((t4 & 7) == 7) {
            DP[(size_t)b * 160 + h * 10 + (t4 >> 3)] = (accS - accF) * 0.0625f;
            accF = 0.f; accS = 0.f;
        }
        ev = en; cv = cn;
    }
}

// ---------- Kernel C: fc1+fc2, 4 batch per block ----------
__global__ void __launch_bounds__(256)
fc_kernel(const float* __restrict__ DP, const float* __restrict__ ws,
          const float* __restrict__ fc1_b, const float* __restrict__ fc2_b,
          float* __restrict__ out)
{
    __shared__ float sh_dp[4][160];
    __shared__ float mid[4][64];
    const int tid = threadIdx.x;
    const int b0 = blockIdx.x * 4;
    for (int p = tid; p < 640; p += 256)
        sh_dp[p / 160][p - (p / 160) * 160] = DP[(size_t)b0 * 160 + p];
    __syncthreads();
    {
        const int bl = tid >> 6, o = tid & 63;
        const float* __restrict__ fc1t = ws + OFF_FC1T;
        float z = fc1_b[o];
        for (int f = 0; f < 160; ++f) z = fmaf(sh_dp[bl][f], fc1t[f * 64 + o], z);
        mid[bl][o] = fmaxf(z, 0.f);
    }
    __syncthreads();
    if (tid < 16) {
        const int bl = tid >> 2, oo = tid & 3;
        const float* __restrict__ fc2t = ws + OFF_FC2T;
        float z = fc2_b[oo];
        #pragma unroll
        for (int jj = 0; jj < 64; ++jj) z = fmaf(mid[bl][jj], fc2t[jj * 4 + oo], z);
        out[(size_t)(b0 + bl) * 4 + oo] = z;
    }
}

extern "C" void kernel_launch(void* const* d_in, const int* in_sizes, int n_in,
                              void* d_out, int out_size, void* d_ws, size_t ws_size,
                              hipStream_t stream)
{
    const float* xeeg = (const float*)d_in[0];
    const float* xgeo = (const float*)d_in[1];
    const float* c1w  = (const float*)d_in[2];
    const float* c1b  = (const float*)d_in[3];
    const float* s1   = (const float*)d_in[4];
    const float* bb1  = (const float*)d_in[5];
    const float* mm1  = (const float*)d_in[6];
    const float* vv1  = (const float*)d_in[7];
    const float* c2w  = (const float*)d_in[8];
    const float* c2b  = (const float*)d_in[9];
    const float* s2   = (const float*)d_in[10];
    const float* bb2  = (const float*)d_in[11];
    const float* mm2  = (const float*)d_in[12];
    const float* vv2  = (const float*)d_in[13];
    const float* gw   = (const float*)d_in[14];
    const float* gb   = (const float*)d_in[15];
    const float* gam  = (const float*)d_in[16];
    const float* fc1w = (const float*)d_in[17];
    const float* fc1b = (const float*)d_in[18];
    const float* fc2w = (const float*)d_in[19];
    const float* fc2b = (const float*)d_in[20];
    float* ws   = (float*)d_ws;
    float* outp = (float*)d_out;

    hipLaunchKernelGGL(prep_kernel, dim3(1), dim3(256), 0, stream,
                       c1w, c1b, s1, bb1, mm1, vv1, c2w, c2b, s2, bb2, mm2, vv2,
                       gw, fc1w, fc2w, ws);

    float* E  = ws + OFF_E;
    float* C  = ws + OFF_C;
    float* DP = ws + OFF_DP;
    hipLaunchKernelGGL(convm_kernel, dim3(TB), dim3(256), 0, stream,
                       xeeg, xgeo, ws, gb, gam, E, C);
    hipLaunchKernelGGL(scan_kernel, dim3(TB / 16), dim3(256), 0, stream,
                       E, C, DP);
    hipLaunchKernelGGL(fc_kernel, dim3(TB / 4), dim3(256), 0, stream,
                       DP, ws, fc1b, fc2b, outp);
}